// Round 2
// baseline (425.709 us; speedup 1.0000x reference)
//
#include <hip/hip_runtime.h>
#include <stdint.h>

#define TT 300
#define DD 40
#define SB 4               // samples per block; grid 512 -> 2 blocks/CU for cross-block latency hiding
#define AROW 200           // halfwords per A row; word stride 100 -> bank stride 4 -> 2-way = free
#define ABUF (16 * AROW)   // 3200 halfwords per A buffer

typedef __attribute__((ext_vector_type(8))) short short8;
typedef __attribute__((ext_vector_type(4))) float f32x4;

__device__ __forceinline__ ushort f2bf(float f) {
  uint32_t b = __float_as_uint(f);
  b += 0x7FFFu + ((b >> 16) & 1u);   // RNE
  return (ushort)(b >> 16);
}

// Barrier that does NOT drain vmcnt: LDS ops retired (lgkmcnt), global loads stay in flight.
__device__ __forceinline__ void bar() {
  asm volatile("s_waitcnt lgkmcnt(0)" ::: "memory");
  __builtin_amdgcn_s_barrier();
  asm volatile("" ::: "memory");
}

// K layout (192 = 6 ktiles of 32):
//   k  0..39  : x_t
//   k 40,41   : 1.0 (bf16) -> bias hi/lo folded into the matmul
//   k 42..63  : zero
//   k 64..191 : h interleaved: 64+2u = h_hi(u), 65+2u = h_lo(u); both use W row 40+u
// Column permutation: ntile g holds gate g -> lane (n=lane&15) owns the full (i,j,f,o)
// quad of unit u = wv*16 + n in acc0..acc3 at rows (lane>>4)*4 + r.
// Sample row remap: sample s in A row 4*(s>>1)+(s&1) (rows {0,1,4,5}) -> lane group
// q = lane>>4 (q<2) sees samples (2q, 2q+1) at regs r=0,1.
__global__ __launch_bounds__(256, 1) void lstm_mfma_kernel(
    const float* __restrict__ X, const int* __restrict__ seqlen,
    const float* __restrict__ Wk, const float* __restrict__ bias,
    float* __restrict__ hfin)
{
  __shared__ ushort wstage[64 * 192];   // 24 KB, init-only staging (one wave's 64 cols)
  __shared__ ushort Ash[2 * ABUF];      // 12.8 KB, double-buffered A (bf16)

  const int tid = threadIdx.x;
  const int wv = tid >> 6, lane = tid & 63;
  const int s0 = blockIdx.x * SB;

  for (int i = tid; i < 2 * ABUF; i += 256) Ash[i] = 0;

  // ---- stage B fragments into registers (24 frags = 96 VGPRs/wave) ----
  // B[k][n] fragment layout: n = lane&15, k = ktile*32 + (lane>>4)*8 + j
  short8 Bf[6][4];
  for (int c = 0; c < 4; ++c) {
    __syncthreads();   // zero-loop done (c=0); wave c-1's frag reads drained
    for (int i = tid; i < 64 * 192; i += 256) {
      int cc = i & 63, kp = i >> 6;
      int g = cc >> 4, u = c * 16 + (cc & 15);
      int col = g * 64 + u;
      ushort v = 0;
      if (kp < 40) {
        v = f2bf(Wk[kp * 256 + col]);
      } else if (kp < 42) {               // bias as ones-row weights, hi + lo residual
        float bv = bias[col] + ((g == 2) ? 1.0f : 0.0f);   // forget-gate +1
        ushort hi = f2bf(bv);
        v = (kp == 40) ? hi : f2bf(bv - __uint_as_float((uint32_t)hi << 16));
      } else if (kp >= 64) {
        v = f2bf(Wk[(40 + ((kp - 64) >> 1)) * 256 + col]); // hi and lo share the weight row
      }
      wstage[cc * 192 + kp] = v;
    }
    __syncthreads();
    if (wv == c) {
      #pragma unroll
      for (int kt = 0; kt < 6; ++kt) {
        int kk = kt * 32 + (lane >> 4) * 8;
        #pragma unroll
        for (int g = 0; g < 4; ++g)
          Bf[kt][g] = *reinterpret_cast<const short8*>(
              &wstage[(g * 16 + (lane & 15)) * 192 + kk]);
      }
    }
  }

  // ---- per-lane ownership ----
  const int u = wv * 16 + (lane & 15);
  const int q = lane >> 4;
  const bool act = (q < 2);                    // lane groups 0,1 own real samples
  const int sl0 = 2 * q, sl1 = sl0 + 1;
  const int len0 = seqlen[s0 + (sl0 & 3)], len1 = seqlen[s0 + (sl1 & 3)];

  int ml = seqlen[s0 + (lane & 3)];            // block-max seqlen
  #pragma unroll
  for (int off = 1; off < 4; off <<= 1) ml = max(ml, __shfl_xor(ml, off));

  // x prefetch: 160 values/step; threads 0..159 own one (sample, dim) slot
  const bool hasX = (tid < SB * DD);
  const int sA = (tid * 205) >> 13, dA = tid - sA * 40;
  const int rA = 4 * (sA >> 1) + (sA & 1);
  const float* pA = X + (size_t)(s0 + sA) * (TT * DD) + dA;
  const int xiA = rA * AROW + dA;

  // ones at k=40,41 for the 4 real rows, BOTH buffers (never overwritten afterwards)
  if (tid < 8) {
    int s = tid & 3, b = tid >> 2;
    int row = 4 * (s >> 1) + (s & 1);
    Ash[b * ABUF + row * AROW + 40] = 0x3F80;
    Ash[b * ABUF + row * AROW + 41] = 0x3F80;
  }
  float xv = 0.f;                              // x(t+1), consumed at step t
  if (hasX) {
    Ash[xiA] = f2bf(pA[0]);                    // x_0 into buffer 0
    if (ml > 1) xv = pA[DD];                   // x(1)
  }
  __syncthreads();
  pA += 2 * DD;                                // points at x(t+2) for t=0

  float c0 = 0.f, c1 = 0.f, hf0 = 0.f, hf1 = 0.f;
  int rb = 0, wb = ABUF;
  const int afb = (lane & 15) * AROW + q * 8;
  const int hw0 = (q * 4) * AROW + 64 + 2 * u;       // row 4q   (sample sl0)
  const int hw1 = (q * 4 + 1) * AROW + 64 + 2 * u;   // row 4q+1 (sample sl1)

  for (int t = 0; t < ml; ++t) {
    // A fragments: A[m=lane&15][k = kt*32 + q*8 + j]   (2-way bank alias only -> free)
    short8 Af[6];
    #pragma unroll
    for (int kt = 0; kt < 6; ++kt)
      Af[kt] = *reinterpret_cast<const short8*>(&Ash[rb + afb + kt * 32]);

    // issue x(t+2) load now; consumed NEXT iteration (one full step of latency slack,
    // survives the barrier because bar() leaves vmcnt alone)
    float xn = 0.f;
    if (hasX && t + 2 < ml) { xn = pA[0]; pA += DD; }

    f32x4 zero4 = {0.f, 0.f, 0.f, 0.f};
    f32x4 acc0 = zero4, acc1 = zero4, acc2 = zero4, acc3 = zero4;
    #pragma unroll
    for (int kt = 0; kt < 6; ++kt) {
      acc0 = __builtin_amdgcn_mfma_f32_16x16x32_bf16(Af[kt], Bf[kt][0], acc0, 0, 0, 0);
      acc1 = __builtin_amdgcn_mfma_f32_16x16x32_bf16(Af[kt], Bf[kt][1], acc1, 0, 0, 0);
      acc2 = __builtin_amdgcn_mfma_f32_16x16x32_bf16(Af[kt], Bf[kt][2], acc2, 0, 0, 0);
      acc3 = __builtin_amdgcn_mfma_f32_16x16x32_bf16(Af[kt], Bf[kt][3], acc3, 0, 0, 0);
    }

    if (act) {
      // acc0=i acc1=j acc2=f acc3=o (bias already in); r=0 -> sl0, r=1 -> sl1.
      // sigm(i)*tanh(j) = (Ej-1)*rcp((1+Ei)(1+Ej)); tanh(nc)*sigm(o) likewise.
      float Ef0 = __expf(-acc2[0]), Ei0 = __expf(-acc0[0]), Ej0 = __expf(2.f * acc1[0]);
      float nc0 = fmaf(c0, __builtin_amdgcn_rcpf(1.f + Ef0),
                       (Ej0 - 1.f) * __builtin_amdgcn_rcpf((1.f + Ei0) * (1.f + Ej0)));
      float En0 = __expf(2.f * fminf(nc0, 44.f)), Eo0 = __expf(-acc3[0]);
      float nh0 = (En0 - 1.f) * __builtin_amdgcn_rcpf((1.f + En0) * (1.f + Eo0));

      float Ef1 = __expf(-acc2[1]), Ei1 = __expf(-acc0[1]), Ej1 = __expf(2.f * acc1[1]);
      float nc1 = fmaf(c1, __builtin_amdgcn_rcpf(1.f + Ef1),
                       (Ej1 - 1.f) * __builtin_amdgcn_rcpf((1.f + Ei1) * (1.f + Ej1)));
      float En1 = __expf(2.f * fminf(nc1, 44.f)), Eo1 = __expf(-acc3[1]);
      float nh1 = (En1 - 1.f) * __builtin_amdgcn_rcpf((1.f + En1) * (1.f + Eo1));

      c0 = nc0; c1 = nc1;
      if (t == len0 - 1) hf0 = nh0;
      if (t == len1 - 1) hf1 = nh1;

      // h feedback as bf16 hi+lo, one packed b32 write per sample, into the NEXT buffer
      ushort hh0 = f2bf(nh0);
      ushort hl0 = f2bf(nh0 - __uint_as_float((uint32_t)hh0 << 16));
      ushort hh1 = f2bf(nh1);
      ushort hl1 = f2bf(nh1 - __uint_as_float((uint32_t)hh1 << 16));
      *reinterpret_cast<uint32_t*>(&Ash[wb + hw0]) = (uint32_t)hh0 | ((uint32_t)hl0 << 16);
      *reinterpret_cast<uint32_t*>(&Ash[wb + hw1]) = (uint32_t)hh1 | ((uint32_t)hl1 << 16);
    }
    if (hasX && t + 1 < ml) Ash[wb + xiA] = f2bf(xv);   // x(t+1), loaded last iteration

    bar();   // single barrier/step: publishes buf[t+1], retires reads of buf[t]; vmcnt untouched
    rb ^= ABUF; wb ^= ABUF;
    xv = xn;
  }

  if (act) {
    hfin[(size_t)(s0 + sl0) * 64 + u] = hf0;
    hfin[(size_t)(s0 + sl1) * 64 + u] = hf1;
  }
}

// head: 16 samples per block (128 blocks) -> W2 read 128x instead of 2048x
__global__ __launch_bounds__(256, 1) void head_kernel(
    const float* __restrict__ hfin,
    const float* __restrict__ W1, const float* __restrict__ b1,
    const float* __restrict__ gamma, const float* __restrict__ beta,
    const float* __restrict__ mmean, const float* __restrict__ mvar,
    const float* __restrict__ W2, const float* __restrict__ b2,
    float* __restrict__ out)
{
  __shared__ float hl[16 * 64];     // 4 KB
  __shared__ float d1t[128 * 20];   // transposed d1 [k][s], stride 20 (16B-aligned)
  __shared__ float lg[16 * 516];    // 33 KB logits
  const int tid = threadIdx.x;
  const int b0 = blockIdx.x * 16;

  for (int i = tid; i < 16 * 64; i += 256) hl[i] = hfin[(size_t)b0 * 64 + i];
  __syncthreads();

  { // dense1 + BN + ReLU: thread = (col j, sample-group sg), 8 samples each
    const int j = tid & 127, sg = tid >> 7;
    float acc[8];
    const float bb = b1[j];
    #pragma unroll
    for (int s = 0; s < 8; ++s) acc[s] = bb;
    for (int k = 0; k < 64; ++k) {
      float w = W1[k * 128 + j];
      #pragma unroll
      for (int s = 0; s < 8; ++s) acc[s] = fmaf(hl[(sg * 8 + s) * 64 + k], w, acc[s]);
    }
    const float ga = gamma[j], be = beta[j], mm = mmean[j];
    const float iv = rsqrtf(mvar[j] + 1e-3f);
    #pragma unroll
    for (int s = 0; s < 8; ++s) {
      float v = fmaxf(acc[s], 0.f);
      d1t[j * 20 + sg * 8 + s] = ga * (v - mm) * iv + be;
    }
  }
  __syncthreads();

  { // logits: thread owns cols 2*tid, 2*tid+1 for all 16 samples
    const int cA = tid * 2;
    float accA[16], accB[16];
    const float bA = b2[cA], bB = b2[cA + 1];
    #pragma unroll
    for (int s = 0; s < 16; ++s) { accA[s] = bA; accB[s] = bB; }
    for (int k = 0; k < 128; ++k) {
      const float2 w = *reinterpret_cast<const float2*>(&W2[k * 512 + cA]);
      const f32x4 dq0 = *reinterpret_cast<const f32x4*>(&d1t[k * 20]);
      const f32x4 dq1 = *reinterpret_cast<const f32x4*>(&d1t[k * 20 + 4]);
      const f32x4 dq2 = *reinterpret_cast<const f32x4*>(&d1t[k * 20 + 8]);
      const f32x4 dq3 = *reinterpret_cast<const f32x4*>(&d1t[k * 20 + 12]);
      #pragma unroll
      for (int s = 0; s < 4; ++s) {
        accA[s]      = fmaf(dq0[s], w.x, accA[s]);      accB[s]      = fmaf(dq0[s], w.y, accB[s]);
        accA[s + 4]  = fmaf(dq1[s], w.x, accA[s + 4]);  accB[s + 4]  = fmaf(dq1[s], w.y, accB[s + 4]);
        accA[s + 8]  = fmaf(dq2[s], w.x, accA[s + 8]);  accB[s + 8]  = fmaf(dq2[s], w.y, accB[s + 8]);
        accA[s + 12] = fmaf(dq3[s], w.x, accA[s + 12]); accB[s + 12] = fmaf(dq3[s], w.y, accB[s + 12]);
      }
    }
    #pragma unroll
    for (int s = 0; s < 16; ++s) {
      lg[s * 516 + cA]     = accA[s];
      lg[s * 516 + cA + 1] = accB[s];
    }
  }
  __syncthreads();

  { // softmax: wave handles 4 samples, 8 cols/lane
    const int w = tid >> 6, lane = tid & 63;
    #pragma unroll
    for (int si = 0; si < 4; ++si) {
      const int s = w * 4 + si;
      float v[8];
      float m = -3.4e38f;
      #pragma unroll
      for (int i = 0; i < 8; ++i) { v[i] = lg[s * 516 + lane + 64 * i]; m = fmaxf(m, v[i]); }
      #pragma unroll
      for (int off = 1; off < 64; off <<= 1) m = fmaxf(m, __shfl_xor(m, off));
      float sum = 0.f;
      #pragma unroll
      for (int i = 0; i < 8; ++i) { v[i] = __expf(v[i] - m); sum += v[i]; }
      #pragma unroll
      for (int off = 1; off < 64; off <<= 1) sum += __shfl_xor(sum, off);
      const float inv = __builtin_amdgcn_rcpf(sum);
      #pragma unroll
      for (int i = 0; i < 8; ++i)
        out[(size_t)(b0 + s) * 512 + lane + 64 * i] = v[i] * inv;
    }
  }
}

extern "C" void kernel_launch(void* const* d_in, const int* in_sizes, int n_in,
                              void* d_out, int out_size, void* d_ws, size_t ws_size,
                              hipStream_t stream) {
  const float* X      = (const float*)d_in[0];
  const int*   seqlen = (const int*)d_in[1];
  const float* Wk     = (const float*)d_in[2];
  const float* bias   = (const float*)d_in[3];
  const float* W1     = (const float*)d_in[4];
  const float* b1     = (const float*)d_in[5];
  const float* gam    = (const float*)d_in[6];
  const float* bet    = (const float*)d_in[7];
  const float* mmean  = (const float*)d_in[8];
  const float* mvar   = (const float*)d_in[9];
  const float* W2     = (const float*)d_in[10];
  const float* b2     = (const float*)d_in[11];
  float* out  = (float*)d_out;
  float* hfin = (float*)d_ws;   // 2048*64 fp32 = 512 KB

  lstm_mfma_kernel<<<dim3(2048 / SB), dim3(256), 0, stream>>>(X, seqlen, Wk, bias, hfin);
  head_kernel<<<dim3(128), dim3(256), 0, stream>>>(hfin, W1, b1, gam, bet,
                                                   mmean, mvar, W2, b2, out);
}

// Round 3
// 398.100 us; speedup vs baseline: 1.0693x; 1.0693x over previous
//
#include <hip/hip_runtime.h>
#include <stdint.h>

#define TT 300
#define DD 40
#define SB 8               // samples per block; grid 256 -> 1 block/CU
#define AROW 200           // halfwords per A row; word stride 100 -> bank stride 4 -> 2-way = free
#define ABUF (16 * AROW)   // 3200 halfwords per A buffer

typedef __attribute__((ext_vector_type(8))) short short8;
typedef __attribute__((ext_vector_type(4))) float f32x4;

__device__ __forceinline__ ushort f2bf(float f) {
  uint32_t b = __float_as_uint(f);
  b += 0x7FFFu + ((b >> 16) & 1u);   // RNE
  return (ushort)(b >> 16);
}

// Barrier that does NOT drain vmcnt: LDS ops retired (lgkmcnt), global loads stay in flight.
__device__ __forceinline__ void bar() {
  asm volatile("s_waitcnt lgkmcnt(0)" ::: "memory");
  __builtin_amdgcn_s_barrier();
  asm volatile("" ::: "memory");
}

// K layout (192 = 6 ktiles of 32):
//   k  0..39  : x_t
//   k 40,41   : 1.0 (bf16) -> bias hi/lo folded into the matmul
//   k 42..63  : zero
//   k 64..191 : h interleaved: 64+2u = h_hi(u), 65+2u = h_lo(u); both use W row 40+u
// Column permutation: ntile g holds gate g -> lane (n=lane&15) owns the full (i,j,f,o)
// quad of unit u = wv*16 + n in acc0..acc3 at rows (lane>>4)*4 + r.
// Sample row remap: sample s in A row 4*(s>>1)+(s&1) (rows {0,1,4,5,8,9,12,13}) ->
// lane group q = lane>>4 sees samples (2q, 2q+1) at regs r=0,1.
__global__ __launch_bounds__(256, 1) void lstm_mfma_kernel(
    const float* __restrict__ X, const int* __restrict__ seqlen,
    const float* __restrict__ Wk, const float* __restrict__ bias,
    float* __restrict__ hfin)
{
  __shared__ ushort shmem[64 * 192];   // 24 KB: B-staging first, then A double-buffer
  ushort* const Ash = shmem;

  const int tid = threadIdx.x;
  const int wv = tid >> 6, lane = tid & 63;
  const int s0 = blockIdx.x * SB;

  // ---- stage B fragments into registers (24 frags = 96 VGPRs/wave) ----
  // B[k][n] fragment layout: n = lane&15, k = ktile*32 + (lane>>4)*8 + j
  short8 Bf[6][4];
  for (int c = 0; c < 4; ++c) {
    for (int i = tid; i < 64 * 192; i += 256) {
      int cc = i & 63, kp = i >> 6;
      int g = cc >> 4, u = c * 16 + (cc & 15);
      int col = g * 64 + u;
      ushort v = 0;
      if (kp < 40) {
        v = f2bf(Wk[kp * 256 + col]);
      } else if (kp < 42) {               // bias as ones-row weights, hi + lo residual
        float bv = bias[col] + ((g == 2) ? 1.0f : 0.0f);   // forget-gate +1
        ushort hi = f2bf(bv);
        v = (kp == 40) ? hi : f2bf(bv - __uint_as_float((uint32_t)hi << 16));
      } else if (kp >= 64) {
        v = f2bf(Wk[(40 + ((kp - 64) >> 1)) * 256 + col]); // hi and lo share the weight row
      }
      shmem[cc * 192 + kp] = v;
    }
    __syncthreads();
    if (wv == c) {
      #pragma unroll
      for (int kt = 0; kt < 6; ++kt) {
        int kk = kt * 32 + (lane >> 4) * 8;
        #pragma unroll
        for (int g = 0; g < 4; ++g)
          Bf[kt][g] = *reinterpret_cast<const short8*>(
              &shmem[(g * 16 + (lane & 15)) * 192 + kk]);
      }
    }
    __syncthreads();   // protects wave c's frag reads from next fill / Ash reuse
  }

  // ---- reuse shmem as the A double-buffer ----
  for (int i = tid; i < 2 * ABUF; i += 256) Ash[i] = 0;

  // ---- per-lane ownership ----
  const int u = wv * 16 + (lane & 15);
  const int q = lane >> 4;
  const int sl0 = 2 * q, sl1 = sl0 + 1;
  const int len0 = seqlen[s0 + sl0], len1 = seqlen[s0 + sl1];

  int ml = seqlen[s0 + (lane & 7)];            // block-max seqlen (values repeat every 8 lanes)
  #pragma unroll
  for (int off = 1; off < 8; off <<= 1) ml = max(ml, __shfl_xor(ml, off));

  // x prefetch: 320 values/step; thread covers i=tid and (tid<64) i=tid+256
  const int iA = tid, iB = 256 + tid;
  const int sA = (iA * 205) >> 13, dA = iA - sA * 40;
  int sB = (iB * 205) >> 13; if (sB > 7) sB = 7;
  const int dB = iB - sB * 40;
  const int rA = 4 * (sA >> 1) + (sA & 1), rB = 4 * (sB >> 1) + (sB & 1);
  const float* pA = X + (size_t)(s0 + sA) * (TT * DD) + dA;
  const float* pB = X + (size_t)(s0 + sB) * (TT * DD) + dB;
  const bool hasB = (iB < SB * DD);
  const int xiA = rA * AROW + dA, xiB = rB * AROW + dB;

  // ones at k=40,41 for the 8 real rows, BOTH buffers (never overwritten afterwards)
  if (tid < 16) {
    int s = tid & 7, b = tid >> 3;
    int row = 4 * (s >> 1) + (s & 1);
    Ash[b * ABUF + row * AROW + 40] = 0x3F80;
    Ash[b * ABUF + row * AROW + 41] = 0x3F80;
  }
  Ash[xiA] = f2bf(pA[0]);                      // x_0 into buffer 0
  if (hasB) Ash[xiB] = f2bf(pB[0]);
  float xvA = 0.f, xvB = 0.f;                  // x(t+1), consumed at step t
  if (ml > 1) {
    xvA = pA[DD];
    if (hasB) xvB = pB[DD];
  }
  __syncthreads();
  pA += 2 * DD; pB += 2 * DD;                  // point at x(t+2) for t=0

  float c0 = 0.f, c1 = 0.f, hf0 = 0.f, hf1 = 0.f;
  int rb = 0, wb = ABUF;
  const int afb = (lane & 15) * AROW + q * 8;
  const int hw0 = (q * 4) * AROW + 64 + 2 * u;       // row 4q   (sample sl0)
  const int hw1 = (q * 4 + 1) * AROW + 64 + 2 * u;   // row 4q+1 (sample sl1)

  for (int t = 0; t < ml; ++t) {
    // --- h-dependent part FIRST (the loop-carried chain): kt 2..5 ---
    short8 Ah[4];
    #pragma unroll
    for (int k2 = 0; k2 < 4; ++k2)
      Ah[k2] = *reinterpret_cast<const short8*>(&Ash[rb + afb + (k2 + 2) * 32]);

    f32x4 zero4 = {0.f, 0.f, 0.f, 0.f};
    f32x4 ah0 = zero4, ah1 = zero4, ah2 = zero4, ah3 = zero4;
    #pragma unroll
    for (int k2 = 0; k2 < 4; ++k2) {
      ah0 = __builtin_amdgcn_mfma_f32_16x16x32_bf16(Ah[k2], Bf[k2 + 2][0], ah0, 0, 0, 0);
      ah1 = __builtin_amdgcn_mfma_f32_16x16x32_bf16(Ah[k2], Bf[k2 + 2][1], ah1, 0, 0, 0);
      ah2 = __builtin_amdgcn_mfma_f32_16x16x32_bf16(Ah[k2], Bf[k2 + 2][2], ah2, 0, 0, 0);
      ah3 = __builtin_amdgcn_mfma_f32_16x16x32_bf16(Ah[k2], Bf[k2 + 2][3], ah3, 0, 0, 0);
    }

    // --- x part in the shadow of the h-MFMA latency: kt 0..1 ---
    short8 Ax[2];
    #pragma unroll
    for (int k2 = 0; k2 < 2; ++k2)
      Ax[k2] = *reinterpret_cast<const short8*>(&Ash[rb + afb + k2 * 32]);

    // publish x(t+1) (loaded last iteration) into the NEXT buffer
    if (t + 1 < ml) {
      Ash[wb + xiA] = f2bf(xvA);
      if (hasB) Ash[wb + xiB] = f2bf(xvB);
    }
    // issue x(t+2) load; consumed next iteration (a full step of latency slack;
    // survives the barrier because bar() leaves vmcnt alone)
    float xnA = 0.f, xnB = 0.f;
    if (t + 2 < ml) {
      xnA = pA[0]; pA += DD;
      if (hasB) { xnB = pB[0]; pB += DD; }
    }

    f32x4 ax0 = zero4, ax1 = zero4, ax2 = zero4, ax3 = zero4;
    #pragma unroll
    for (int k2 = 0; k2 < 2; ++k2) {
      ax0 = __builtin_amdgcn_mfma_f32_16x16x32_bf16(Ax[k2], Bf[k2][0], ax0, 0, 0, 0);
      ax1 = __builtin_amdgcn_mfma_f32_16x16x32_bf16(Ax[k2], Bf[k2][1], ax1, 0, 0, 0);
      ax2 = __builtin_amdgcn_mfma_f32_16x16x32_bf16(Ax[k2], Bf[k2][2], ax2, 0, 0, 0);
      ax3 = __builtin_amdgcn_mfma_f32_16x16x32_bf16(Ax[k2], Bf[k2][3], ax3, 0, 0, 0);
    }
    f32x4 z0 = ah0 + ax0, z1 = ah1 + ax1, z2 = ah2 + ax2, z3 = ah3 + ax3;

    // z0=i z1=j z2=f z3=o (bias already in); r=0 -> sl0, r=1 -> sl1.
    // sigm(i)*tanh(j) = (Ej-1)*rcp((1+Ei)(1+Ej)); tanh(nc)*sigm(o) likewise.
    float Ef0 = __expf(-z2[0]), Ei0 = __expf(-z0[0]), Ej0 = __expf(2.f * z1[0]);
    float nc0 = fmaf(c0, __builtin_amdgcn_rcpf(1.f + Ef0),
                     (Ej0 - 1.f) * __builtin_amdgcn_rcpf((1.f + Ei0) * (1.f + Ej0)));
    float En0 = __expf(2.f * fminf(nc0, 44.f)), Eo0 = __expf(-z3[0]);
    float nh0 = (En0 - 1.f) * __builtin_amdgcn_rcpf((1.f + En0) * (1.f + Eo0));

    float Ef1 = __expf(-z2[1]), Ei1 = __expf(-z0[1]), Ej1 = __expf(2.f * z1[1]);
    float nc1 = fmaf(c1, __builtin_amdgcn_rcpf(1.f + Ef1),
                     (Ej1 - 1.f) * __builtin_amdgcn_rcpf((1.f + Ei1) * (1.f + Ej1)));
    float En1 = __expf(2.f * fminf(nc1, 44.f)), Eo1 = __expf(-z3[1]);
    float nh1 = (En1 - 1.f) * __builtin_amdgcn_rcpf((1.f + En1) * (1.f + Eo1));

    c0 = nc0; c1 = nc1;
    if (t == len0 - 1) hf0 = nh0;
    if (t == len1 - 1) hf1 = nh1;

    // h feedback: TRUNCATED hi (residual lo captures the error) -> shorter tail
    ushort hh0 = (ushort)(__float_as_uint(nh0) >> 16);
    ushort hl0 = f2bf(nh0 - __uint_as_float((uint32_t)hh0 << 16));
    ushort hh1 = (ushort)(__float_as_uint(nh1) >> 16);
    ushort hl1 = f2bf(nh1 - __uint_as_float((uint32_t)hh1 << 16));
    *reinterpret_cast<uint32_t*>(&Ash[wb + hw0]) = (uint32_t)hh0 | ((uint32_t)hl0 << 16);
    *reinterpret_cast<uint32_t*>(&Ash[wb + hw1]) = (uint32_t)hh1 | ((uint32_t)hl1 << 16);

    bar();   // single barrier/step: publishes buf[t+1], retires reads of buf[t]; vmcnt untouched
    rb ^= ABUF; wb ^= ABUF;
    xvA = xnA; xvB = xnB;
  }

  hfin[(size_t)(s0 + sl0) * 64 + u] = hf0;
  hfin[(size_t)(s0 + sl1) * 64 + u] = hf1;
}

// head: 16 samples per block (128 blocks) -> W2 read 128x instead of 2048x
__global__ __launch_bounds__(256, 1) void head_kernel(
    const float* __restrict__ hfin,
    const float* __restrict__ W1, const float* __restrict__ b1,
    const float* __restrict__ gamma, const float* __restrict__ beta,
    const float* __restrict__ mmean, const float* __restrict__ mvar,
    const float* __restrict__ W2, const float* __restrict__ b2,
    float* __restrict__ out)
{
  __shared__ float hl[16 * 64];     // 4 KB
  __shared__ float d1t[128 * 20];   // transposed d1 [k][s], stride 20 (16B-aligned)
  __shared__ float lg[16 * 516];    // 33 KB logits
  const int tid = threadIdx.x;
  const int b0 = blockIdx.x * 16;

  for (int i = tid; i < 16 * 64; i += 256) hl[i] = hfin[(size_t)b0 * 64 + i];
  __syncthreads();

  { // dense1 + BN + ReLU: thread = (col j, sample-group sg), 8 samples each
    const int j = tid & 127, sg = tid >> 7;
    float acc[8];
    const float bb = b1[j];
    #pragma unroll
    for (int s = 0; s < 8; ++s) acc[s] = bb;
    for (int k = 0; k < 64; ++k) {
      float w = W1[k * 128 + j];
      #pragma unroll
      for (int s = 0; s < 8; ++s) acc[s] = fmaf(hl[(sg * 8 + s) * 64 + k], w, acc[s]);
    }
    const float ga = gamma[j], be = beta[j], mm = mmean[j];
    const float iv = rsqrtf(mvar[j] + 1e-3f);
    #pragma unroll
    for (int s = 0; s < 8; ++s) {
      float v = fmaxf(acc[s], 0.f);
      d1t[j * 20 + sg * 8 + s] = ga * (v - mm) * iv + be;
    }
  }
  __syncthreads();

  { // logits: thread owns cols 2*tid, 2*tid+1 for all 16 samples
    const int cA = tid * 2;
    float accA[16], accB[16];
    const float bA = b2[cA], bB = b2[cA + 1];
    #pragma unroll
    for (int s = 0; s < 16; ++s) { accA[s] = bA; accB[s] = bB; }
    for (int k = 0; k < 128; ++k) {
      const float2 w = *reinterpret_cast<const float2*>(&W2[k * 512 + cA]);
      const f32x4 dq0 = *reinterpret_cast<const f32x4*>(&d1t[k * 20]);
      const f32x4 dq1 = *reinterpret_cast<const f32x4*>(&d1t[k * 20 + 4]);
      const f32x4 dq2 = *reinterpret_cast<const f32x4*>(&d1t[k * 20 + 8]);
      const f32x4 dq3 = *reinterpret_cast<const f32x4*>(&d1t[k * 20 + 12]);
      #pragma unroll
      for (int s = 0; s < 4; ++s) {
        accA[s]      = fmaf(dq0[s], w.x, accA[s]);      accB[s]      = fmaf(dq0[s], w.y, accB[s]);
        accA[s + 4]  = fmaf(dq1[s], w.x, accA[s + 4]);  accB[s + 4]  = fmaf(dq1[s], w.y, accB[s + 4]);
        accA[s + 8]  = fmaf(dq2[s], w.x, accA[s + 8]);  accB[s + 8]  = fmaf(dq2[s], w.y, accB[s + 8]);
        accA[s + 12] = fmaf(dq3[s], w.x, accA[s + 12]); accB[s + 12] = fmaf(dq3[s], w.y, accB[s + 12]);
      }
    }
    #pragma unroll
    for (int s = 0; s < 16; ++s) {
      lg[s * 516 + cA]     = accA[s];
      lg[s * 516 + cA + 1] = accB[s];
    }
  }
  __syncthreads();

  { // softmax: wave handles 4 samples, 8 cols/lane
    const int w = tid >> 6, lane = tid & 63;
    #pragma unroll
    for (int si = 0; si < 4; ++si) {
      const int s = w * 4 + si;
      float v[8];
      float m = -3.4e38f;
      #pragma unroll
      for (int i = 0; i < 8; ++i) { v[i] = lg[s * 516 + lane + 64 * i]; m = fmaxf(m, v[i]); }
      #pragma unroll
      for (int off = 1; off < 64; off <<= 1) m = fmaxf(m, __shfl_xor(m, off));
      float sum = 0.f;
      #pragma unroll
      for (int i = 0; i < 8; ++i) { v[i] = __expf(v[i] - m); sum += v[i]; }
      #pragma unroll
      for (int off = 1; off < 64; off <<= 1) sum += __shfl_xor(sum, off);
      const float inv = __builtin_amdgcn_rcpf(sum);
      #pragma unroll
      for (int i = 0; i < 8; ++i)
        out[(size_t)(b0 + s) * 512 + lane + 64 * i] = v[i] * inv;
    }
  }
}

extern "C" void kernel_launch(void* const* d_in, const int* in_sizes, int n_in,
                              void* d_out, int out_size, void* d_ws, size_t ws_size,
                              hipStream_t stream) {
  const float* X      = (const float*)d_in[0];
  const int*   seqlen = (const int*)d_in[1];
  const float* Wk     = (const float*)d_in[2];
  const float* bias   = (const float*)d_in[3];
  const float* W1     = (const float*)d_in[4];
  const float* b1     = (const float*)d_in[5];
  const float* gam    = (const float*)d_in[6];
  const float* bet    = (const float*)d_in[7];
  const float* mmean  = (const float*)d_in[8];
  const float* mvar   = (const float*)d_in[9];
  const float* W2     = (const float*)d_in[10];
  const float* b2     = (const float*)d_in[11];
  float* out  = (float*)d_out;
  float* hfin = (float*)d_ws;   // 2048*64 fp32 = 512 KB

  lstm_mfma_kernel<<<dim3(2048 / SB), dim3(256), 0, stream>>>(X, seqlen, Wk, bias, hfin);
  head_kernel<<<dim3(128), dim3(256), 0, stream>>>(hfin, W1, b1, gam, bet,
                                                   mmean, mvar, W2, b2, out);
}

// Round 4
// 365.000 us; speedup vs baseline: 1.1663x; 1.0907x over previous
//
#include <hip/hip_runtime.h>
#include <stdint.h>

#define TT 300
#define DD 40
#define SB 8                      // samples per block; grid 256
#define AROWH 192                 // halfwords per A row (16B-aligned rows; banks fixed by XOR swizzle)
#define ABYTES (16 * AROWH * 2)   // 6144 bytes per A buffer
#define WROW 224                  // staging stride in halfwords (448 B rows, 16B aligned)

typedef __attribute__((ext_vector_type(8))) short short8;
typedef __attribute__((ext_vector_type(4))) float f32x4;

__device__ __forceinline__ ushort f2bf(float f) {
  uint32_t b = __float_as_uint(f);
  b += 0x7FFFu + ((b >> 16) & 1u);   // RNE
  return (ushort)(b >> 16);
}

// Barrier that does NOT drain vmcnt: LDS ops retired (lgkmcnt), global loads stay in flight.
__device__ __forceinline__ void bar() {
  asm volatile("s_waitcnt lgkmcnt(0)" ::: "memory");
  __builtin_amdgcn_s_barrier();
  asm volatile("" ::: "memory");
}

// Swizzled byte offset into the A tile: row-major [16][AROWH] bf16 with
// byte ^= (row&7)<<4. Rows are 384 B (≡0 mod 128) so the XOR stays inside the
// row and preserves 16B alignment; A-frag ds_read_b128 becomes 2-way (free).
__device__ __forceinline__ int aswz(int row, int colh) {
  return ((row * AROWH + colh) * 2) ^ ((row & 7) << 4);
}

// K layout (192 = 6 ktiles of 32):
//   k  0..39  : x_t
//   k 40,41   : 1.0 (bf16) -> bias hi/lo folded into the matmul
//   k 42..63  : zero
//   k 64..191 : h interleaved: 64+2u = h_hi(u), 65+2u = h_lo(u); both use W row 40+u
// 8 waves, wave wv owns units 8wv..8wv+7 as 2 ntiles of 16 cols:
//   ntile nt, frag col nb -> gate g = nt + 2*(nb>>3), unit u = 8wv + (nb&7)
//   => lane (q=lane>>4, n=lane&15, m=n&7, b=n>>3) gets gates (b?f:i) in acc0 and
//      (b?o:j) in acc1 for unit 8wv+m; the other two gates come from lane n^8
//      via 4 __shfl_xor. Each lane handles ONE (sample,unit): sample 2q+b, unit 8wv+m.
// Sample row remap: sample s lives in A row 4*(s>>1)+(s&1).
__global__ __launch_bounds__(512, 2) void lstm_mfma_kernel(
    const float* __restrict__ X, const int* __restrict__ seqlen,
    const float* __restrict__ Wk, const float* __restrict__ bias,
    float* __restrict__ hfin)
{
  __shared__ ushort shmem[64 * WROW];   // 28 KB; first 12288 B reused as A double-buffer
  char* const Ab = reinterpret_cast<char*>(shmem);

  const int tid = threadIdx.x;
  const int wv = tid >> 6, lane = tid & 63;
  const int q = lane >> 4, n = lane & 15, m = n & 7, b = n >> 3;
  const int s0 = blockIdx.x * SB;

  // ---- stage B fragments into registers (12 frags = 48 VGPRs/wave) ----
  // B[k][nb] fragment layout: nb = lane&15, k = ktile*32 + (lane>>4)*8 + j
  short8 Bf[6][2];
  for (int c = 0; c < 4; ++c) {          // round c stages cols for waves 2c, 2c+1
    for (int i = tid; i < 64 * 192; i += 512) {
      int cc = i & 63, kp = i >> 6;
      int nb = cc & 15, nt = (cc >> 4) & 1, ws = cc >> 5;
      int g = nt + 2 * (nb >> 3);
      int uu = (2 * c + ws) * 8 + (nb & 7);
      int col = g * 64 + uu;
      ushort v = 0;
      if (kp < 40) {
        v = f2bf(Wk[kp * 256 + col]);
      } else if (kp < 42) {              // bias as ones-row weights, hi + lo residual
        float bv = bias[col] + ((g == 2) ? 1.0f : 0.0f);   // forget-gate +1
        ushort hi = f2bf(bv);
        v = (kp == 40) ? hi : f2bf(bv - __uint_as_float((uint32_t)hi << 16));
      } else if (kp >= 64) {
        v = f2bf(Wk[(40 + ((kp - 64) >> 1)) * 256 + col]); // hi and lo share the weight row
      }
      shmem[cc * WROW + kp] = v;
    }
    __syncthreads();
    if ((wv >> 1) == c) {
      const int cbase = (wv & 1) * 32;
      #pragma unroll
      for (int kt = 0; kt < 6; ++kt) {
        #pragma unroll
        for (int nt = 0; nt < 2; ++nt)
          Bf[kt][nt] = *reinterpret_cast<const short8*>(
              &shmem[(cbase + nt * 16 + n) * WROW + kt * 32 + q * 8]);
      }
    }
    __syncthreads();                     // protect frag reads from next round's fill
  }

  // ---- reuse shmem[0..12288B) as the A double-buffer; zero it ----
  for (int i = tid; i < 6144; i += 512) shmem[i] = 0;
  __syncthreads();                       // zeros visible before ones/x0 writes (cross-wave)

  // ---- per-lane ownership: ONE (sample, unit) pair ----
  const int u = wv * 8 + m;
  const int sl = 2 * q + b;
  const int len = seqlen[s0 + sl];
  int ml = seqlen[s0 + (lane & 7)];      // block-max seqlen
  #pragma unroll
  for (int off = 1; off < 8; off <<= 1) ml = max(ml, __shfl_xor(ml, off));

  // x prefetch: 320 values/step; threads 0..319 own one (sample, dim) slot
  const bool hasX = (tid < SB * DD);
  const int sA = (tid * 205) >> 13, dA = tid - sA * 40;   // exact for tid<320
  const int rA = 4 * (sA >> 1) + (sA & 1);
  const float* pA = X + (size_t)(s0 + sA) * (TT * DD) + dA;
  const int xb = aswz(rA, dA);

  if (tid < 16) {   // ones at k=40,41 for the 8 real rows, BOTH buffers
    int s = tid & 7, bb = tid >> 3;
    int row = 4 * (s >> 1) + (s & 1);
    *reinterpret_cast<uint32_t*>(Ab + bb * ABYTES + aswz(row, 40)) = 0x3F803F80u;
  }
  float xv = 0.f;                        // x(t+1), consumed at step t
  if (hasX) {
    *reinterpret_cast<ushort*>(Ab + xb) = f2bf(pA[0]);    // x_0 into buffer 0
    if (ml > 1) xv = pA[DD];
  }
  __syncthreads();
  pA += 2 * DD;                          // points at x(t+2) for t=0

  // A-frag swizzled byte offsets (loop-invariant, constant-indexed -> registers)
  int aoff[6];
  #pragma unroll
  for (int kt = 0; kt < 6; ++kt)
    aoff[kt] = (n * 384 + kt * 64 + q * 16) ^ (m << 4);

  float cst = 0.f, hf = 0.f;
  int rb = 0, wb = ABYTES;
  const int hb = aswz(4 * q + b, 64 + 2 * u);   // my sample's h slot (4B aligned)

  for (int t = 0; t < ml; ++t) {
    // --- h-dependent part FIRST (the loop-carried chain): kt 2..5 ---
    short8 Ah[4];
    #pragma unroll
    for (int k2 = 0; k2 < 4; ++k2)
      Ah[k2] = *reinterpret_cast<const short8*>(Ab + rb + aoff[k2 + 2]);

    f32x4 zero4 = {0.f, 0.f, 0.f, 0.f};
    f32x4 ah0 = zero4, ah1 = zero4;
    #pragma unroll
    for (int k2 = 0; k2 < 4; ++k2) {
      ah0 = __builtin_amdgcn_mfma_f32_16x16x32_bf16(Ah[k2], Bf[k2 + 2][0], ah0, 0, 0, 0);
      ah1 = __builtin_amdgcn_mfma_f32_16x16x32_bf16(Ah[k2], Bf[k2 + 2][1], ah1, 0, 0, 0);
    }

    // --- x part in the shadow of the h-MFMA latency: kt 0..1 ---
    short8 Ax0 = *reinterpret_cast<const short8*>(Ab + rb + aoff[0]);
    short8 Ax1 = *reinterpret_cast<const short8*>(Ab + rb + aoff[1]);

    // publish x(t+1) (loaded last iteration) into the NEXT buffer
    if (hasX && t + 1 < ml) *reinterpret_cast<ushort*>(Ab + wb + xb) = f2bf(xv);
    // issue x(t+2) load; consumed next iteration (full step of slack; bar() leaves vmcnt alone)
    float xn = 0.f;
    if (hasX && t + 2 < ml) { xn = pA[0]; pA += DD; }

    f32x4 ax0 = zero4, ax1 = zero4;
    ax0 = __builtin_amdgcn_mfma_f32_16x16x32_bf16(Ax0, Bf[0][0], ax0, 0, 0, 0);
    ax1 = __builtin_amdgcn_mfma_f32_16x16x32_bf16(Ax0, Bf[0][1], ax1, 0, 0, 0);
    ax0 = __builtin_amdgcn_mfma_f32_16x16x32_bf16(Ax1, Bf[1][0], ax0, 0, 0, 0);
    ax1 = __builtin_amdgcn_mfma_f32_16x16x32_bf16(Ax1, Bf[1][1], ax1, 0, 0, 0);

    f32x4 z0 = ah0 + ax0, z1 = ah1 + ax1;

    // gather the 4 gates of MY (sample,unit): partner lane n^8 holds the other pair
    float p00 = __shfl_xor(z0[0], 8);
    float p01 = __shfl_xor(z0[1], 8);
    float p10 = __shfl_xor(z1[0], 8);
    float p11 = __shfl_xor(z1[1], 8);
    float gi = b ? p01 : z0[0];
    float gf = b ? z0[1] : p00;
    float gj = b ? p11 : z1[0];
    float go = b ? z1[1] : p10;

    // sigm(i)*tanh(j) = (Ej-1)*rcp((1+Ei)(1+Ej)); tanh(nc)*sigm(o) likewise. Bias already in.
    float Ef = __expf(-gf), Ei = __expf(-gi), Ej = __expf(2.f * gj);
    float nc = fmaf(cst, __builtin_amdgcn_rcpf(1.f + Ef),
                    (Ej - 1.f) * __builtin_amdgcn_rcpf((1.f + Ei) * (1.f + Ej)));
    float En = __expf(2.f * fminf(nc, 44.f)), Eo = __expf(-go);
    float nh = (En - 1.f) * __builtin_amdgcn_rcpf((1.f + En) * (1.f + Eo));
    cst = nc;
    if (t == len - 1) hf = nh;

    // h feedback: truncated hi (residual lo captures the error), one b32 write
    ushort hh = (ushort)(__float_as_uint(nh) >> 16);
    ushort hl = f2bf(nh - __uint_as_float((uint32_t)hh << 16));
    *reinterpret_cast<uint32_t*>(Ab + wb + hb) = (uint32_t)hh | ((uint32_t)hl << 16);

    bar();   // single barrier/step: publishes buf[t+1], retires reads of buf[t]; vmcnt untouched
    rb ^= ABYTES; wb ^= ABYTES;
    xv = xn;
  }

  hfin[(size_t)(s0 + sl) * 64 + u] = hf;
}

// head: 16 samples per block (128 blocks) -> W2 read 128x instead of 2048x
__global__ __launch_bounds__(256, 1) void head_kernel(
    const float* __restrict__ hfin,
    const float* __restrict__ W1, const float* __restrict__ b1,
    const float* __restrict__ gamma, const float* __restrict__ beta,
    const float* __restrict__ mmean, const float* __restrict__ mvar,
    const float* __restrict__ W2, const float* __restrict__ b2,
    float* __restrict__ out)
{
  __shared__ float hl[16 * 64];     // 4 KB
  __shared__ float d1t[128 * 20];   // transposed d1 [k][s], stride 20 (16B-aligned)
  __shared__ float lg[16 * 516];    // 33 KB logits
  const int tid = threadIdx.x;
  const int b0 = blockIdx.x * 16;

  for (int i = tid; i < 16 * 64; i += 256) hl[i] = hfin[(size_t)b0 * 64 + i];
  __syncthreads();

  { // dense1 + BN + ReLU: thread = (col j, sample-group sg), 8 samples each
    const int j = tid & 127, sg = tid >> 7;
    float acc[8];
    const float bb = b1[j];
    #pragma unroll
    for (int s = 0; s < 8; ++s) acc[s] = bb;
    for (int k = 0; k < 64; ++k) {
      float w = W1[k * 128 + j];
      #pragma unroll
      for (int s = 0; s < 8; ++s) acc[s] = fmaf(hl[(sg * 8 + s) * 64 + k], w, acc[s]);
    }
    const float ga = gamma[j], be = beta[j], mm = mmean[j];
    const float iv = rsqrtf(mvar[j] + 1e-3f);
    #pragma unroll
    for (int s = 0; s < 8; ++s) {
      float v = fmaxf(acc[s], 0.f);
      d1t[j * 20 + sg * 8 + s] = ga * (v - mm) * iv + be;
    }
  }
  __syncthreads();

  { // logits: thread owns cols 2*tid, 2*tid+1 for all 16 samples
    const int cA = tid * 2;
    float accA[16], accB[16];
    const float bA = b2[cA], bB = b2[cA + 1];
    #pragma unroll
    for (int s = 0; s < 16; ++s) { accA[s] = bA; accB[s] = bB; }
    for (int k = 0; k < 128; ++k) {
      const float2 w = *reinterpret_cast<const float2*>(&W2[k * 512 + cA]);
      const f32x4 dq0 = *reinterpret_cast<const f32x4*>(&d1t[k * 20]);
      const f32x4 dq1 = *reinterpret_cast<const f32x4*>(&d1t[k * 20 + 4]);
      const f32x4 dq2 = *reinterpret_cast<const f32x4*>(&d1t[k * 20 + 8]);
      const f32x4 dq3 = *reinterpret_cast<const f32x4*>(&d1t[k * 20 + 12]);
      #pragma unroll
      for (int s = 0; s < 4; ++s) {
        accA[s]      = fmaf(dq0[s], w.x, accA[s]);      accB[s]      = fmaf(dq0[s], w.y, accB[s]);
        accA[s + 4]  = fmaf(dq1[s], w.x, accA[s + 4]);  accB[s + 4]  = fmaf(dq1[s], w.y, accB[s + 4]);
        accA[s + 8]  = fmaf(dq2[s], w.x, accA[s + 8]);  accB[s + 8]  = fmaf(dq2[s], w.y, accB[s + 8]);
        accA[s + 12] = fmaf(dq3[s], w.x, accA[s + 12]); accB[s + 12] = fmaf(dq3[s], w.y, accB[s + 12]);
      }
    }
    #pragma unroll
    for (int s = 0; s < 16; ++s) {
      lg[s * 516 + cA]     = accA[s];
      lg[s * 516 + cA + 1] = accB[s];
    }
  }
  __syncthreads();

  { // softmax: wave handles 4 samples, 8 cols/lane
    const int w = tid >> 6, lane = tid & 63;
    #pragma unroll
    for (int si = 0; si < 4; ++si) {
      const int s = w * 4 + si;
      float v[8];
      float mx = -3.4e38f;
      #pragma unroll
      for (int i = 0; i < 8; ++i) { v[i] = lg[s * 516 + lane + 64 * i]; mx = fmaxf(mx, v[i]); }
      #pragma unroll
      for (int off = 1; off < 64; off <<= 1) mx = fmaxf(mx, __shfl_xor(mx, off));
      float sum = 0.f;
      #pragma unroll
      for (int i = 0; i < 8; ++i) { v[i] = __expf(v[i] - mx); sum += v[i]; }
      #pragma unroll
      for (int off = 1; off < 64; off <<= 1) sum += __shfl_xor(sum, off);
      const float inv = __builtin_amdgcn_rcpf(sum);
      #pragma unroll
      for (int i = 0; i < 8; ++i)
        out[(size_t)(b0 + s) * 512 + lane + 64 * i] = v[i] * inv;
    }
  }
}

extern "C" void kernel_launch(void* const* d_in, const int* in_sizes, int n_in,
                              void* d_out, int out_size, void* d_ws, size_t ws_size,
                              hipStream_t stream) {
  const float* X      = (const float*)d_in[0];
  const int*   seqlen = (const int*)d_in[1];
  const float* Wk     = (const float*)d_in[2];
  const float* bias   = (const float*)d_in[3];
  const float* W1     = (const float*)d_in[4];
  const float* b1     = (const float*)d_in[5];
  const float* gam    = (const float*)d_in[6];
  const float* bet    = (const float*)d_in[7];
  const float* mmean  = (const float*)d_in[8];
  const float* mvar   = (const float*)d_in[9];
  const float* W2     = (const float*)d_in[10];
  const float* b2     = (const float*)d_in[11];
  float* out  = (float*)d_out;
  float* hfin = (float*)d_ws;   // 2048*64 fp32 = 512 KB

  lstm_mfma_kernel<<<dim3(2048 / SB), dim3(512), 0, stream>>>(X, seqlen, Wk, bias, hfin);
  head_kernel<<<dim3(128), dim3(256), 0, stream>>>(hfin, W1, b1, gam, bet,
                                                   mmean, mvar, W2, b2, out);
}

// Round 5
// 363.464 us; speedup vs baseline: 1.1713x; 1.0042x over previous
//
#include <hip/hip_runtime.h>
#include <stdint.h>

#define TT 300
#define DD 40
#define SB 8                      // samples per block; grid 256
#define AROWH 192                 // halfwords per A row (16B-aligned rows; banks fixed by XOR swizzle)
#define ABYTES (16 * AROWH * 2)   // 6144 bytes per A buffer
#define WROW 224                  // staging stride in halfwords (448 B rows, 16B aligned)

typedef __attribute__((ext_vector_type(8))) short short8;
typedef __attribute__((ext_vector_type(4))) float f32x4;

__device__ __forceinline__ ushort f2bf(float f) {
  uint32_t b = __float_as_uint(f);
  b += 0x7FFFu + ((b >> 16) & 1u);   // RNE
  return (ushort)(b >> 16);
}

// Barrier that does NOT drain vmcnt: LDS ops retired (lgkmcnt), global loads stay in flight.
__device__ __forceinline__ void bar() {
  asm volatile("s_waitcnt lgkmcnt(0)" ::: "memory");
  __builtin_amdgcn_s_barrier();
  asm volatile("" ::: "memory");
}

// Swizzled byte offset into the A tile: row-major [16][AROWH] bf16 with
// byte ^= (row&7)<<4. Rows are 384 B (≡0 mod 128) so the XOR stays inside the
// row and preserves 16B alignment; A-frag ds_read_b128 becomes 2-way (free).
__device__ __forceinline__ int aswz(int row, int colh) {
  return ((row * AROWH + colh) * 2) ^ ((row & 7) << 4);
}

// K layout (192 = 6 ktiles of 32):
//   k  0..39  : x_t
//   k 40,41   : 1.0 (bf16) -> bias hi/lo folded into the matmul
//   k 42..63  : zero
//   k 64..191 : h interleaved: 64+2u = h_hi(u), 65+2u = h_lo(u); both use W row 40+u
// 8 waves, wave wv owns units 8wv..8wv+7 as 2 ntiles of 16 cols:
//   ntile nt, frag col nb -> gate g = nt + 2*(nb>>3), unit u = 8wv + (nb&7)
//   => lane (q=lane>>4, n=lane&15, m=n&7, b=n>>3) gets gates (b?f:i) in z0 and
//      (b?o:j) in z1 for unit 8wv+m; the other two gates come from lane n^8
//      via 4 __shfl_xor. Each lane handles ONE (sample,unit): sample 2q+b, unit 8wv+m.
// Sample row remap: sample s lives in A row 4*(s>>1)+(s&1).
__global__ __launch_bounds__(512, 2) void lstm_mfma_kernel(
    const float* __restrict__ X, const int* __restrict__ seqlen,
    const float* __restrict__ Wk, const float* __restrict__ bias,
    float* __restrict__ hfin)
{
  __shared__ ushort shmem[64 * WROW];   // 28 KB; first 12288 B reused as A double-buffer
  char* const Ab = reinterpret_cast<char*>(shmem);

  const int tid = threadIdx.x;
  const int wv = tid >> 6, lane = tid & 63;
  const int q = lane >> 4, n = lane & 15, m = n & 7, b = n >> 3;
  const int s0 = blockIdx.x * SB;

  // ---- stage B fragments into registers (12 frags = 48 VGPRs/wave) ----
  // B[k][nb] fragment layout: nb = lane&15, k = ktile*32 + (lane>>4)*8 + j
  short8 Bf[6][2];
  for (int c = 0; c < 4; ++c) {          // round c stages cols for waves 2c, 2c+1
    for (int i = tid; i < 64 * 192; i += 512) {
      int cc = i & 63, kp = i >> 6;
      int nb = cc & 15, nt = (cc >> 4) & 1, ws = cc >> 5;
      int g = nt + 2 * (nb >> 3);
      int uu = (2 * c + ws) * 8 + (nb & 7);
      int col = g * 64 + uu;
      ushort v = 0;
      if (kp < 40) {
        v = f2bf(Wk[kp * 256 + col]);
      } else if (kp < 42) {              // bias as ones-row weights, hi + lo residual
        float bv = bias[col] + ((g == 2) ? 1.0f : 0.0f);   // forget-gate +1
        ushort hi = f2bf(bv);
        v = (kp == 40) ? hi : f2bf(bv - __uint_as_float((uint32_t)hi << 16));
      } else if (kp >= 64) {
        v = f2bf(Wk[(40 + ((kp - 64) >> 1)) * 256 + col]); // hi and lo share the weight row
      }
      shmem[cc * WROW + kp] = v;
    }
    __syncthreads();
    if ((wv >> 1) == c) {
      const int cbase = (wv & 1) * 32;
      #pragma unroll
      for (int kt = 0; kt < 6; ++kt) {
        #pragma unroll
        for (int nt = 0; nt < 2; ++nt)
          Bf[kt][nt] = *reinterpret_cast<const short8*>(
              &shmem[(cbase + nt * 16 + n) * WROW + kt * 32 + q * 8]);
      }
    }
    __syncthreads();                     // protect frag reads from next round's fill
  }

  // ---- reuse shmem[0..12288B) as the A double-buffer; zero it ----
  for (int i = tid; i < 6144; i += 512) shmem[i] = 0;
  __syncthreads();                       // zeros visible before ones/x0 writes (cross-wave)

  // ---- per-lane ownership: ONE (sample, unit) pair ----
  const int u = wv * 8 + m;
  const int sl = 2 * q + b;
  const int len = seqlen[s0 + sl];
  int ml = seqlen[s0 + (lane & 7)];      // block-max seqlen
  #pragma unroll
  for (int off = 1; off < 8; off <<= 1) ml = max(ml, __shfl_xor(ml, off));

  // x prefetch: 320 values/step; threads 0..319 own one (sample, dim) slot
  const bool hasX = (tid < SB * DD);
  const int sA = (tid * 205) >> 13, dA = tid - sA * 40;   // exact for tid<320
  const int rA = 4 * (sA >> 1) + (sA & 1);
  const float* pA = X + (size_t)(s0 + sA) * (TT * DD) + dA;
  const int xb = aswz(rA, dA);

  if (tid < 16) {   // ones at k=40,41 for the 8 real rows, BOTH buffers
    int s = tid & 7, bb = tid >> 3;
    int row = 4 * (s >> 1) + (s & 1);
    *reinterpret_cast<uint32_t*>(Ab + bb * ABYTES + aswz(row, 40)) = 0x3F803F80u;
  }
  float xv = 0.f;                        // x(t+1), consumed at step t
  if (hasX) {
    *reinterpret_cast<ushort*>(Ab + xb) = f2bf(pA[0]);    // x_0 into buffer 0
    if (ml > 1) xv = pA[DD];
  }
  __syncthreads();
  pA += 2 * DD;                          // points at x(t+2) for t=0

  // A-frag swizzled byte offsets (loop-invariant, constant-indexed -> registers)
  int aoff[6];
  #pragma unroll
  for (int kt = 0; kt < 6; ++kt)
    aoff[kt] = (n * 384 + kt * 64 + q * 16) ^ (m << 4);

  float cst = 0.f, hf = 0.f;
  int rb = 0, wb = ABYTES;
  const int hb = aswz(4 * q + b, 64 + 2 * u);   // my sample's h slot (4B aligned)

  for (int t = 0; t < ml; ++t) {
    // --- x-frags FIRST: ready since last barrier; x-MFMAs fill the h ds_read shadow ---
    short8 Ax0 = *reinterpret_cast<const short8*>(Ab + rb + aoff[0]);
    short8 Ax1 = *reinterpret_cast<const short8*>(Ab + rb + aoff[1]);
    short8 Ah[4];
    #pragma unroll
    for (int k2 = 0; k2 < 4; ++k2)
      Ah[k2] = *reinterpret_cast<const short8*>(Ab + rb + aoff[k2 + 2]);

    f32x4 zero4 = {0.f, 0.f, 0.f, 0.f};
    f32x4 ac0[2], ac1[2], ac2[2], ac3[2];
    #pragma unroll
    for (int nt = 0; nt < 2; ++nt) {
      ac0[nt] = __builtin_amdgcn_mfma_f32_16x16x32_bf16(Ax0, Bf[0][nt], zero4, 0, 0, 0);
      ac0[nt] = __builtin_amdgcn_mfma_f32_16x16x32_bf16(Ax1, Bf[1][nt], ac0[nt], 0, 0, 0);
    }

    // publish x(t+1) (loaded last iteration) into the NEXT buffer; issue x(t+2) load
    if (hasX && t + 1 < ml) *reinterpret_cast<ushort*>(Ab + wb + xb) = f2bf(xv);
    float xn = 0.f;
    if (hasX && t + 2 < ml) { xn = pA[0]; pA += DD; }

    // --- h part: 4 INDEPENDENT accumulators -> chain = last read + ONE mfma + 2 adds ---
    #pragma unroll
    for (int nt = 0; nt < 2; ++nt) {
      ac1[nt] = __builtin_amdgcn_mfma_f32_16x16x32_bf16(Ah[0], Bf[2][nt], zero4, 0, 0, 0);
      ac2[nt] = __builtin_amdgcn_mfma_f32_16x16x32_bf16(Ah[1], Bf[3][nt], zero4, 0, 0, 0);
      ac3[nt] = __builtin_amdgcn_mfma_f32_16x16x32_bf16(Ah[2], Bf[4][nt], zero4, 0, 0, 0);
      ac0[nt] = __builtin_amdgcn_mfma_f32_16x16x32_bf16(Ah[3], Bf[5][nt], ac0[nt], 0, 0, 0);
    }
    f32x4 z0 = (ac0[0] + ac1[0]) + (ac2[0] + ac3[0]);
    f32x4 z1 = (ac0[1] + ac1[1]) + (ac2[1] + ac3[1]);

    // gather the 4 gates of MY (sample,unit): partner lane n^8 holds the other pair
    float p00 = __shfl_xor(z0[0], 8);
    float p01 = __shfl_xor(z0[1], 8);
    float p10 = __shfl_xor(z1[0], 8);
    float p11 = __shfl_xor(z1[1], 8);
    float gi = b ? p01 : z0[0];
    float gf = b ? z0[1] : p00;
    float gj = b ? p11 : z1[0];
    float go = b ? z1[1] : p10;

    // sigm(i)*tanh(j) = (Ej-1)*rcp((1+Ei)(1+Ej)); tanh(nc)*sigm(o) likewise. Bias already in.
    float Ef = __expf(-gf), Ei = __expf(-gi), Ej = __expf(2.f * gj);
    float nc = fmaf(cst, __builtin_amdgcn_rcpf(1.f + Ef),
                    (Ej - 1.f) * __builtin_amdgcn_rcpf((1.f + Ei) * (1.f + Ej)));
    float En = __expf(2.f * fminf(nc, 44.f)), Eo = __expf(-go);
    float nh = (En - 1.f) * __builtin_amdgcn_rcpf((1.f + En) * (1.f + Eo));
    cst = nc;
    if (t == len - 1) hf = nh;

    // h feedback: truncated hi + truncated lo residual (total err ~2^-18), one b32 write
    ushort hh = (ushort)(__float_as_uint(nh) >> 16);
    float rem = nh - __uint_as_float((uint32_t)hh << 16);
    ushort hl = (ushort)(__float_as_uint(rem) >> 16);
    *reinterpret_cast<uint32_t*>(Ab + wb + hb) = (uint32_t)hh | ((uint32_t)hl << 16);

    bar();   // single barrier/step: publishes buf[t+1], retires reads of buf[t]; vmcnt untouched
    rb ^= ABYTES; wb ^= ABYTES;
    xv = xn;
  }

  hfin[(size_t)(s0 + sl) * 64 + u] = hf;
}

// head: 16 samples per block (128 blocks) -> W2 read 128x instead of 2048x
__global__ __launch_bounds__(256, 1) void head_kernel(
    const float* __restrict__ hfin,
    const float* __restrict__ W1, const float* __restrict__ b1,
    const float* __restrict__ gamma, const float* __restrict__ beta,
    const float* __restrict__ mmean, const float* __restrict__ mvar,
    const float* __restrict__ W2, const float* __restrict__ b2,
    float* __restrict__ out)
{
  __shared__ float hl[16 * 64];     // 4 KB
  __shared__ float d1t[128 * 20];   // transposed d1 [k][s], stride 20 (16B-aligned)
  __shared__ float lg[16 * 516];    // 33 KB logits
  const int tid = threadIdx.x;
  const int b0 = blockIdx.x * 16;

  for (int i = tid; i < 16 * 64; i += 256) hl[i] = hfin[(size_t)b0 * 64 + i];
  __syncthreads();

  { // dense1 + BN + ReLU: thread = (col j, sample-group sg), 8 samples each
    const int j = tid & 127, sg = tid >> 7;
    float acc[8];
    const float bb = b1[j];
    #pragma unroll
    for (int s = 0; s < 8; ++s) acc[s] = bb;
    for (int k = 0; k < 64; ++k) {
      float w = W1[k * 128 + j];
      #pragma unroll
      for (int s = 0; s < 8; ++s) acc[s] = fmaf(hl[(sg * 8 + s) * 64 + k], w, acc[s]);
    }
    const float ga = gamma[j], be = beta[j], mm = mmean[j];
    const float iv = rsqrtf(mvar[j] + 1e-3f);
    #pragma unroll
    for (int s = 0; s < 8; ++s) {
      float v = fmaxf(acc[s], 0.f);
      d1t[j * 20 + sg * 8 + s] = ga * (v - mm) * iv + be;
    }
  }
  __syncthreads();

  { // logits: thread owns cols 2*tid, 2*tid+1 for all 16 samples
    const int cA = tid * 2;
    float accA[16], accB[16];
    const float bA = b2[cA], bB = b2[cA + 1];
    #pragma unroll
    for (int s = 0; s < 16; ++s) { accA[s] = bA; accB[s] = bB; }
    for (int k = 0; k < 128; ++k) {
      const float2 w = *reinterpret_cast<const float2*>(&W2[k * 512 + cA]);
      const f32x4 dq0 = *reinterpret_cast<const f32x4*>(&d1t[k * 20]);
      const f32x4 dq1 = *reinterpret_cast<const f32x4*>(&d1t[k * 20 + 4]);
      const f32x4 dq2 = *reinterpret_cast<const f32x4*>(&d1t[k * 20 + 8]);
      const f32x4 dq3 = *reinterpret_cast<const f32x4*>(&d1t[k * 20 + 12]);
      #pragma unroll
      for (int s = 0; s < 4; ++s) {
        accA[s]      = fmaf(dq0[s], w.x, accA[s]);      accB[s]      = fmaf(dq0[s], w.y, accB[s]);
        accA[s + 4]  = fmaf(dq1[s], w.x, accA[s + 4]);  accB[s + 4]  = fmaf(dq1[s], w.y, accB[s + 4]);
        accA[s + 8]  = fmaf(dq2[s], w.x, accA[s + 8]);  accB[s + 8]  = fmaf(dq2[s], w.y, accB[s + 8]);
        accA[s + 12] = fmaf(dq3[s], w.x, accA[s + 12]); accB[s + 12] = fmaf(dq3[s], w.y, accB[s + 12]);
      }
    }
    #pragma unroll
    for (int s = 0; s < 16; ++s) {
      lg[s * 516 + cA]     = accA[s];
      lg[s * 516 + cA + 1] = accB[s];
    }
  }
  __syncthreads();

  { // softmax: wave handles 4 samples, 8 cols/lane
    const int w = tid >> 6, lane = tid & 63;
    #pragma unroll
    for (int si = 0; si < 4; ++si) {
      const int s = w * 4 + si;
      float v[8];
      float mx = -3.4e38f;
      #pragma unroll
      for (int i = 0; i < 8; ++i) { v[i] = lg[s * 516 + lane + 64 * i]; mx = fmaxf(mx, v[i]); }
      #pragma unroll
      for (int off = 1; off < 64; off <<= 1) mx = fmaxf(mx, __shfl_xor(mx, off));
      float sum = 0.f;
      #pragma unroll
      for (int i = 0; i < 8; ++i) { v[i] = __expf(v[i] - mx); sum += v[i]; }
      #pragma unroll
      for (int off = 1; off < 64; off <<= 1) sum += __shfl_xor(sum, off);
      const float inv = __builtin_amdgcn_rcpf(sum);
      #pragma unroll
      for (int i = 0; i < 8; ++i)
        out[(size_t)(b0 + s) * 512 + lane + 64 * i] = v[i] * inv;
    }
  }
}

extern "C" void kernel_launch(void* const* d_in, const int* in_sizes, int n_in,
                              void* d_out, int out_size, void* d_ws, size_t ws_size,
                              hipStream_t stream) {
  const float* X      = (const float*)d_in[0];
  const int*   seqlen = (const int*)d_in[1];
  const float* Wk     = (const float*)d_in[2];
  const float* bias   = (const float*)d_in[3];
  const float* W1     = (const float*)d_in[4];
  const float* b1     = (const float*)d_in[5];
  const float* gam    = (const float*)d_in[6];
  const float* bet    = (const float*)d_in[7];
  const float* mmean  = (const float*)d_in[8];
  const float* mvar   = (const float*)d_in[9];
  const float* W2     = (const float*)d_in[10];
  const float* b2     = (const float*)d_in[11];
  float* out  = (float*)d_out;
  float* hfin = (float*)d_ws;   // 2048*64 fp32 = 512 KB

  lstm_mfma_kernel<<<dim3(2048 / SB), dim3(512), 0, stream>>>(X, seqlen, Wk, bias, hfin);
  head_kernel<<<dim3(128), dim3(256), 0, stream>>>(hfin, W1, b1, gam, bet,
                                                   mmean, mvar, W2, b2, out);
}